// Round 2
// baseline (1801.570 us; speedup 1.0000x reference)
//
#include <hip/hip_runtime.h>
#include <stdint.h>

typedef unsigned short u16;
typedef unsigned int   u32;
using f32x4 = __attribute__((ext_vector_type(4))) float;
using s16x8 = __attribute__((ext_vector_type(8))) short;

#define NB   132     // batch
#define NS   50      // src len
#define NT   50      // trg len
#define NTD  49      // decoder steps (T-1)
#define NE   128     // emb dim
#define NH   256     // enc hidden
#define NG   768     // 3*H gates
#define NH2  512     // 2*H
#define NA   32      // attn dim
#define NV   10000   // vocab
#define LDW  640     // dec_wih row stride (E+2H)
#define KFC  896     // dec_fc K (Hd+2H+E)

// ---------------- helpers ----------------
static __device__ __forceinline__ float bf2f(u16 u){ union{u32 i; float f;} v; v.i=((u32)u)<<16; return v.f; }
static __device__ __forceinline__ u16 f2bf(float f){ union{float f; u32 i;} v; v.f=f; return (u16)((v.i + 0x7fffu + ((v.i>>16)&1u))>>16); }
static __device__ __forceinline__ u32 pk2(float lo, float hi){ return (u32)f2bf(lo) | ((u32)f2bf(hi)<<16); }
static __device__ __forceinline__ float bflo(u32 u){ union{u32 i; float f;} v; v.i=u<<16; return v.f; }
static __device__ __forceinline__ float bfhi(u32 u){ union{u32 i; float f;} v; v.i=u&0xffff0000u; return v.f; }
static __device__ __forceinline__ float sigm(float x){ return 1.0f/(1.0f+__expf(-x)); }
static __device__ __forceinline__ float tanh_f(float x){
  x = fminf(fmaxf(x,-15.0f),15.0f); float e = __expf(2.0f*x); return (e-1.0f)/(e+1.0f); }

#define UNPK(u, w0, w1) { w0 = bflo(u); w1 = bfhi(u); }

#define GLDS16(g, l) __builtin_amdgcn_global_load_lds( \
    (__attribute__((address_space(1))) void*)(g), \
    (__attribute__((address_space(3))) void*)(l), 16, 0, 0)

// ---------------- f32 -> bf16 convert (8 elems/thread) ----------------
__global__ void cvt_k(const float* __restrict__ in, u16* __restrict__ out, int n8)
{
  int i = blockIdx.x*256 + threadIdx.x;
  if (i >= n8) return;
  float4 a = ((const float4*)in)[(size_t)i*2];
  float4 b = ((const float4*)in)[(size_t)i*2+1];
  uint4 o; o.x = pk2(a.x,a.y); o.y = pk2(a.z,a.w); o.z = pk2(b.x,b.y); o.w = pk2(b.z,b.w);
  *(uint4*)(out + (size_t)i*8) = o;
}

// ---------------- GEMM: C[M,N] = A[M,K]*Bw[N,K]^T (+f32 bias); out bf16 or f32 ----------------
// mode 0: row-major C; mode 1: dec_fc mapping row=b*49+t -> out row b*50+t+1
__global__ __launch_bounds__(256)
void gemm_bt(const u16* __restrict__ A, int lda,
             const u16* __restrict__ Bw, int ldb,
             const float* __restrict__ bias,
             u16* __restrict__ Cb, float* __restrict__ Cf,
             int M, int N, int K, int mode)
{
  __shared__ __align__(16) u16 Al[128*64];
  __shared__ __align__(16) u16 Bl[128*64];
  const int tid  = threadIdx.x;
  const int lane = tid & 63;
  const int wid  = tid >> 6;
  const int m0 = blockIdx.y * 128;
  const int n0 = blockIdx.x * 128;
  const int wr = wid >> 1, wc = wid & 1;
  const int srow = wid*32 + (lane>>3);
  const int scol = (lane&7)*8;

  f32x4 acc[4][4] = {};

  for (int kt = 0; kt < K; kt += 64){
#pragma unroll
    for (int c = 0; c < 4; c++){
      int ra = m0 + srow + c*8; ra = (ra < M) ? ra : (M-1);
      GLDS16(A  + (size_t)ra*lda + kt + scol, &Al[(wid*32 + c*8)*64]);
      int rb = n0 + srow + c*8; rb = (rb < N) ? rb : (N-1);
      GLDS16(Bw + (size_t)rb*ldb + kt + scol, &Bl[(wid*32 + c*8)*64]);
    }
    __syncthreads();
#pragma unroll
    for (int kk = 0; kk < 2; kk++){
      s16x8 fa[4], fb[4];
#pragma unroll
      for (int m = 0; m < 4; m++)
        fa[m] = *(const s16x8*)&Al[(wr*64 + m*16 + (lane&15))*64 + kk*32 + (lane>>4)*8];
#pragma unroll
      for (int n = 0; n < 4; n++)
        fb[n] = *(const s16x8*)&Bl[(wc*64 + n*16 + (lane&15))*64 + kk*32 + (lane>>4)*8];
#pragma unroll
      for (int m = 0; m < 4; m++)
#pragma unroll
        for (int n = 0; n < 4; n++)
          acc[m][n] = __builtin_amdgcn_mfma_f32_16x16x32_bf16(fa[m], fb[n], acc[m][n], 0, 0, 0);
    }
    __syncthreads();
  }

#pragma unroll
  for (int m = 0; m < 4; m++){
#pragma unroll
    for (int i = 0; i < 4; i++){
      int row = m0 + wr*64 + m*16 + (lane>>4)*4 + i;
      if (row >= M) continue;
      size_t ob;
      if (mode == 1){
        int bb = row / NTD, tt = row - bb*NTD;
        ob = (size_t)(bb*NT + tt + 1) * (size_t)N;
      } else {
        ob = (size_t)row * (size_t)N;
      }
#pragma unroll
      for (int n = 0; n < 4; n++){
        int col = n0 + wc*64 + n*16 + (lane&15);
        if (col < N){
          float v = acc[m][n][i];
          if (bias) v += bias[col];
          if (Cf) Cf[ob + col] = v;
          else    Cb[ob + col] = f2bf(v);
        }
      }
    }
  }
}

// ---------------- whh (f32) -> transposed bf16 [32][768][8] ----------------
__global__ void prep_wt(const float* __restrict__ wf, const float* __restrict__ wb,
                        const float* __restrict__ wd, u16* __restrict__ wt)
{
  int g = blockIdx.x % NG;
  int m = blockIdx.x / NG;          // 0,1,2
  const float* w = (m==0) ? wf : ((m==1) ? wb : wd);
  u16* o = wt + (size_t)m * (NG*NH);
  int k = threadIdx.x;              // 256
  o[(size_t)(k>>3)*(NG*8) + (size_t)g*8 + (k&7)] = f2bf(w[(size_t)g*NH + k]);
}

// ---------------- embedding gathers: f32 emb -> bf16 rows ----------------
__global__ void gather_k(const int* __restrict__ src, const int* __restrict__ trg,
                         const float* __restrict__ enc_emb, const float* __restrict__ dec_emb,
                         u16* __restrict__ xemb, u16* __restrict__ embin)
{
  int idx = blockIdx.x*256 + threadIdx.x;  // 8-elem chunk id
  int row = idx >> 4, c = idx & 15;
  const int NR1 = NB*NS, NR2 = NB*NTD;
  const float* ep; u16* op; size_t orow;
  if (row < NR1){
    int id = src[row];
    ep = enc_emb + (size_t)id*NE + c*8; op = xemb; orow = (size_t)row*NE;
  } else if (row < NR1 + NR2){
    int r2 = row - NR1;
    int bb = r2 / NTD, tt = r2 - bb*NTD;
    int id = trg[bb*NT + tt];
    ep = dec_emb + (size_t)id*NE + c*8; op = embin; orow = (size_t)r2*NE;
  } else return;
  float4 a = ((const float4*)ep)[0];
  float4 b = ((const float4*)ep)[1];
  uint4 o; o.x = pk2(a.x,a.y); o.y = pk2(a.z,a.w); o.z = pk2(b.x,b.y); o.w = pk2(b.z,b.w);
  *(uint4*)(op + orow + c*8) = o;
}

__global__ void ufill_k(const u16* __restrict__ embin, u16* __restrict__ U)
{
  int idx = blockIdx.x*256 + threadIdx.x;
  if (idx >= NB*NTD*16) return;
  int row = idx >> 4, c = idx & 15;
  *(uint4*)(U + (size_t)row*KFC + NG + c*8) = *(const uint4*)(embin + (size_t)row*NE + c*8);
}

__global__ void zero_k(float* __restrict__ out)
{
  int idx = blockIdx.x*256 + threadIdx.x;   // per b: 2500 float4 chunks (t=0 row)
  if (idx >= NB*2500) return;
  int bb = idx / 2500, c = idx - bb*2500;
  ((float4*)(out + (size_t)bb*NT*NV))[c] = make_float4(0.f,0.f,0.f,0.f);
}

// ---------------- encoder GRU scan, G=2 batches per block ----------------
__global__ __launch_bounds__(768)
void enc_scan(const u16* __restrict__ wt_all, const float* __restrict__ bhh_f, const float* __restrict__ bhh_b,
              const u16* __restrict__ xp_f, const u16* __restrict__ xp_b,
              u16* __restrict__ enc_out, float* __restrict__ hT)
{
  const int bid = blockIdx.x;               // 0..131
  const int dir = (bid >= NB/2) ? 1 : 0;
  const int b0  = (dir ? (bid - NB/2) : bid) * 2;
  const u16* wt    = wt_all + (size_t)dir * (NG*NH);
  const float* bhh = dir ? bhh_b : bhh_f;
  const u16* xp    = dir ? xp_b : xp_f;
  const int tid = threadIdx.x;

  __shared__ __align__(16) float h[2][NH];
  __shared__ float gh[2][NG];
  if (tid < 2*NH) h[tid>>8][tid&255] = 0.0f;
  const float bsum = bhh[tid];
  __syncthreads();

  for (int i = 0; i < NS; i++){
    int s = dir ? (NS-1-i) : i;
    float s0 = bsum, s1 = bsum;
#pragma unroll 8
    for (int kc = 0; kc < NH/8; kc++){
      uint4 wv = *(const uint4*)(wt + (size_t)kc*(NG*8) + (size_t)tid*8);
      float4 a0 = *(const float4*)&h[0][kc*8];
      float4 a1 = *(const float4*)&h[0][kc*8+4];
      float4 c0 = *(const float4*)&h[1][kc*8];
      float4 c1 = *(const float4*)&h[1][kc*8+4];
      float w0,w1;
      UNPK(wv.x,w0,w1); s0 += w0*a0.x + w1*a0.y; s1 += w0*c0.x + w1*c0.y;
      UNPK(wv.y,w0,w1); s0 += w0*a0.z + w1*a0.w; s1 += w0*c0.z + w1*c0.w;
      UNPK(wv.z,w0,w1); s0 += w0*a1.x + w1*a1.y; s1 += w0*c1.x + w1*c1.y;
      UNPK(wv.w,w0,w1); s0 += w0*a1.z + w1*a1.w; s1 += w0*c1.z + w1*c1.w;
    }
    gh[0][tid] = s0; gh[1][tid] = s1;
    __syncthreads();
    if (tid < 2*NH){
      int i2 = tid>>8, j = tid&255, b = b0 + i2;
      const u16* xr = xp + ((size_t)b*NS + s)*NG;
      float r = sigm(bf2f(xr[j])        + gh[i2][j]);
      float z = sigm(bf2f(xr[NH+j])     + gh[i2][NH+j]);
      float n = tanh_f(bf2f(xr[2*NH+j]) + r*gh[i2][2*NH+j]);
      float hn = (1.0f - z)*n + z*h[i2][j];
      h[i2][j] = hn;
      enc_out[((size_t)b*NS + s)*NH2 + dir*NH + j] = f2bf(hn);
      if (i == NS-1) hT[(size_t)b*NH2 + dir*NH + j] = hn;
    }
    __syncthreads();
  }
}

// ---------------- hidden + enc_proj (f32 weights, bf16 enc_out) ----------------
__global__ __launch_bounds__(256)
void mid_k(const float* __restrict__ hT, const float* __restrict__ fc_w, const float* __restrict__ fc_b,
           const float* __restrict__ attn_w, const float* __restrict__ attn_b,
           const u16* __restrict__ enc_out,
           float* __restrict__ hidden, float* __restrict__ encproj)
{
  const int b = blockIdx.x, t = threadIdx.x;
  __shared__ __align__(16) float hl[NH2];
  hl[t]      = hT[(size_t)b*NH2 + t];
  hl[NH + t] = hT[(size_t)b*NH2 + NH + t];
  __syncthreads();
  {
    float s = fc_b[t];
    const float* wr_ = fc_w + (size_t)t*NH2;
#pragma unroll 8
    for (int k = 0; k < NH2; k += 8){
      float4 w0 = *(const float4*)(wr_ + k);
      float4 w1 = *(const float4*)(wr_ + k + 4);
      float4 a0 = *(const float4*)&hl[k];
      float4 a1 = *(const float4*)&hl[k+4];
      s += w0.x*a0.x + w0.y*a0.y + w0.z*a0.z + w0.w*a0.w
         + w1.x*a1.x + w1.y*a1.y + w1.z*a1.z + w1.w*a1.w;
    }
    hidden[(size_t)b*NH + t] = tanh_f(s);
  }
  for (int idx = t; idx < NS*NA; idx += 256){
    int s_ = idx >> 5, a = idx & 31;
    const u16*  er  = enc_out + ((size_t)b*NS + s_)*NH2;
    const float* wr_ = attn_w + (size_t)a*NG + NH;   // wa_enc row (cols 256..767)
    float s = attn_b[a];
#pragma unroll 8
    for (int k = 0; k < NH2; k += 8){
      float4 w0 = *(const float4*)(wr_ + k);
      float4 w1 = *(const float4*)(wr_ + k + 4);
      uint4  ev = *(const uint4*)(er + k);
      s += w0.x*bflo(ev.x) + w0.y*bfhi(ev.x) + w0.z*bflo(ev.y) + w0.w*bfhi(ev.y)
         + w1.x*bflo(ev.z) + w1.y*bfhi(ev.z) + w1.z*bflo(ev.w) + w1.w*bfhi(ev.w);
    }
    encproj[((size_t)b*NS + s_)*NA + a] = s;
  }
}

// ---------------- decoder recurrence (one block per batch) ----------------
__global__ __launch_bounds__(768)
void dec_k(const float* __restrict__ hidden, const float* __restrict__ encproj,
           const u16* __restrict__ enc_out, const u16* __restrict__ encxw,
           const u16* __restrict__ xpe, const u16* __restrict__ wt_dec,
           const float* __restrict__ dec_bhh, const float* __restrict__ attn_w,
           u16* __restrict__ U)
{
  const int b = blockIdx.x, tid = threadIdx.x;
  __shared__ __align__(16) float h[NH];
  __shared__ float gh[NG];
  __shared__ float xpl[NG];
  __shared__ __align__(16) float hp[NA];
  __shared__ float av[NS];
  if (tid < NH) h[tid] = hidden[(size_t)b*NH + tid];
  const float bsum = dec_bhh[tid];
  __syncthreads();

  for (int t = 0; t < NTD; t++){
    const int m = b*NTD + t;
    // A1: hp = h @ wa_dec^T
    if (tid < NA){
      const float* wr_ = attn_w + (size_t)tid*NG;    // cols 0..255
      float s = 0.0f;
#pragma unroll 8
      for (int k = 0; k < NH; k += 8){
        float4 w0 = *(const float4*)(wr_ + k);
        float4 w1 = *(const float4*)(wr_ + k + 4);
        float4 a0 = *(const float4*)&h[k];
        float4 a1 = *(const float4*)&h[k+4];
        s += w0.x*a0.x + w0.y*a0.y + w0.z*a0.z + w0.w*a0.w
           + w1.x*a1.x + w1.y*a1.y + w1.z*a1.z + w1.w*a1.w;
      }
      hp[tid] = s;
    }
    __syncthreads();
    // A2: energy + softmax (wave 0)
    if (tid < 64){
      float e = -1e30f;
      if (tid < NS){
        const float* ep = encproj + ((size_t)b*NS + tid)*NA;
        float s = 0.0f;
#pragma unroll
        for (int a = 0; a < NA; a++) s += tanh_f(hp[a] + ep[a]);
        e = s;
      }
      float mx = e;
      for (int o = 32; o >= 1; o >>= 1) mx = fmaxf(mx, __shfl_xor(mx, o, 64));
      float p = (tid < NS) ? __expf(e - mx) : 0.0f;
      float sm = p;
      for (int o = 32; o >= 1; o >>= 1) sm += __shfl_xor(sm, o, 64);
      if (tid < NS) av[tid] = p / sm;
    }
    __syncthreads();
    // B: xpl[g] = xpe[m][g] + sum_s av[s]*encxw[b][s][g]; w -> U
    {
      float xv = bf2f(xpe[(size_t)m*NG + tid]);
      const u16* ex = encxw + (size_t)b*NS*NG + tid;
#pragma unroll 10
      for (int s_ = 0; s_ < NS; s_++) xv += av[s_] * bf2f(ex[(size_t)s_*NG]);
      xpl[tid] = xv;
      if (tid < NH2){
        const u16* eo = enc_out + (size_t)b*NS*NH2 + tid;
        float wv = 0.0f;
#pragma unroll 10
        for (int s_ = 0; s_ < NS; s_++) wv += av[s_] * bf2f(eo[(size_t)s_*NH2]);
        U[(size_t)m*KFC + NH + tid] = f2bf(wv);
      }
    }
    // C: gh = h @ dec_whh^T + bhh
    {
      float s = bsum;
#pragma unroll 8
      for (int kc = 0; kc < NH/8; kc++){
        uint4 wv = *(const uint4*)(wt_dec + (size_t)kc*(NG*8) + (size_t)tid*8);
        float4 h0 = *(const float4*)&h[kc*8];
        float4 h1 = *(const float4*)&h[kc*8+4];
        float w0,w1;
        UNPK(wv.x,w0,w1); s += w0*h0.x + w1*h0.y;
        UNPK(wv.y,w0,w1); s += w0*h0.z + w1*h0.w;
        UNPK(wv.z,w0,w1); s += w0*h1.x + w1*h1.y;
        UNPK(wv.w,w0,w1); s += w0*h1.z + w1*h1.w;
      }
      gh[tid] = s;
    }
    __syncthreads();
    // D: pointwise GRU
    if (tid < NH){
      float r = sigm(xpl[tid]         + gh[tid]);
      float z = sigm(xpl[NH+tid]      + gh[NH+tid]);
      float n = tanh_f(xpl[2*NH+tid]  + r*gh[2*NH+tid]);
      float hn = (1.0f - z)*n + z*h[tid];
      h[tid] = hn;
      U[(size_t)m*KFC + tid] = f2bf(hn);
    }
    __syncthreads();
  }
}

// ---------------- host ----------------
extern "C" void kernel_launch(void* const* d_in, const int* in_sizes, int n_in,
                              void* d_out, int out_size, void* d_ws, size_t ws_size,
                              hipStream_t stream)
{
  const int*   src       = (const int*)d_in[0];
  const int*   trg       = (const int*)d_in[1];
  const float* enc_emb   = (const float*)d_in[2];
  const float* enc_wih_f = (const float*)d_in[3];
  const float* enc_whh_f = (const float*)d_in[4];
  const float* enc_bih_f = (const float*)d_in[5];
  const float* enc_bhh_f = (const float*)d_in[6];
  const float* enc_wih_b = (const float*)d_in[7];
  const float* enc_whh_b = (const float*)d_in[8];
  const float* enc_bih_b = (const float*)d_in[9];
  const float* enc_bhh_b = (const float*)d_in[10];
  const float* enc_fc_w  = (const float*)d_in[11];
  const float* enc_fc_b  = (const float*)d_in[12];
  const float* attn_w    = (const float*)d_in[13];
  const float* attn_b    = (const float*)d_in[14];
  const float* dec_emb   = (const float*)d_in[15];
  const float* dec_wih   = (const float*)d_in[16];
  const float* dec_whh   = (const float*)d_in[17];
  const float* dec_bih   = (const float*)d_in[18];
  const float* dec_bhh   = (const float*)d_in[19];
  const float* dec_fc_w  = (const float*)d_in[20];
  const float* dec_fc_b  = (const float*)d_in[21];
  float* out = (float*)d_out;
  char*  ws  = (char*)d_ws;

  size_t o = 0;
  auto alloc = [&](size_t bytes){ size_t r = o; o += (bytes + 255) & ~(size_t)255; return r; };
  const size_t o_xemb   = alloc((size_t)NB*NS*NE*2);
  const size_t o_embin  = alloc((size_t)NB*NTD*NE*2);
  const size_t o_encout = alloc((size_t)NB*NS*NH2*2);
  const size_t o_hidden = alloc((size_t)NB*NH*4);
  const size_t o_eproj  = alloc((size_t)NB*NS*NA*4);
  const size_t o_encxw  = alloc((size_t)NB*NS*NG*2);
  const size_t o_wt     = alloc((size_t)3*NG*NH*2);
  const size_t sz_xp  = (size_t)NB*NS*NG*2;          // 10,137,600
  const size_t sz_U   = (size_t)NB*NTD*KFC*2;        // 11,590,656
  const size_t sz_xpe = (size_t)NB*NTD*NG*2;         //  9,934,848
  const size_t WIHSZ  = (size_t)NG*NE*2;             //    196,608
  const size_t HTSZ   = (size_t)NB*NH2*4;            //    270,336
  size_t sz_R = 2*sz_xp + 2*WIHSZ + HTSZ;
  if (sz_U + sz_xpe > sz_R) sz_R = sz_U + sz_xpe;
  const size_t o_R = alloc(sz_R);
  if (o > ws_size) return;

  u16*   xemb   = (u16*)(ws + o_xemb);
  u16*   embin  = (u16*)(ws + o_embin);
  u16*   encout = (u16*)(ws + o_encout);
  float* hidden = (float*)(ws + o_hidden);
  float* eproj  = (float*)(ws + o_eproj);
  u16*   encxw  = (u16*)(ws + o_encxw);
  u16*   wt     = (u16*)(ws + o_wt);
  // R region, phase 1: [xpf][xpb][wihf_b][wihb_b][hT]
  u16*   xpf    = (u16*)(ws + o_R);
  u16*   xpb    = (u16*)(ws + o_R + sz_xp);
  u16*   wihf_b = (u16*)(ws + o_R + 2*sz_xp);
  u16*   wihb_b = (u16*)(ws + o_R + 2*sz_xp + WIHSZ);
  float* hT     = (float*)(ws + o_R + 2*sz_xp + 2*WIHSZ);
  // R region, phase 2: [U][xpe]
  u16*   U      = (u16*)(ws + o_R);
  u16*   xpe    = (u16*)(ws + o_R + sz_U);
  // aliased over dead xemb..encxw region:
  u16*   dwih_b = (u16*)(ws + o_xemb);               // 983,040 B  (alive steps 8-10)
  u16*   dfc_b  = (u16*)(ws + o_xemb);               // 17,920,000 B (alive steps 13-14)

  // 1. weight preps (f32 -> bf16)
  hipLaunchKernelGGL(prep_wt, dim3(3*NG), dim3(256), 0, stream, enc_whh_f, enc_whh_b, dec_whh, wt);
  hipLaunchKernelGGL(cvt_k, dim3((NG*NE/8+255)/256), dim3(256), 0, stream, enc_wih_f, wihf_b, NG*NE/8);
  hipLaunchKernelGGL(cvt_k, dim3((NG*NE/8+255)/256), dim3(256), 0, stream, enc_wih_b, wihb_b, NG*NE/8);
  // 2. gathers + t=0 zero rows
  {
    int chunks = (NB*NS + NB*NTD) * 16;
    hipLaunchKernelGGL(gather_k, dim3((chunks+255)/256), dim3(256), 0, stream,
                       src, trg, enc_emb, dec_emb, xemb, embin);
  }
  hipLaunchKernelGGL(zero_k, dim3((NB*2500+255)/256), dim3(256), 0, stream, out);
  // 3. encoder input projections
  hipLaunchKernelGGL(gemm_bt, dim3(NG/128, (NB*NS+127)/128), dim3(256), 0, stream,
                     xemb, NE, wihf_b, NE, enc_bih_f, xpf, (float*)nullptr, NB*NS, NG, NE, 0);
  hipLaunchKernelGGL(gemm_bt, dim3(NG/128, (NB*NS+127)/128), dim3(256), 0, stream,
                     xemb, NE, wihb_b, NE, enc_bih_b, xpb, (float*)nullptr, NB*NS, NG, NE, 0);
  // 4. bidirectional GRU scan (G=2 batches/block)
  hipLaunchKernelGGL(enc_scan, dim3(NB), dim3(768), 0, stream,
                     wt, enc_bhh_f, enc_bhh_b, xpf, xpb, encout, hT);
  // 5. hidden + enc_proj
  hipLaunchKernelGGL(mid_k, dim3(NB), dim3(256), 0, stream,
                     hT, enc_fc_w, enc_fc_b, attn_w, attn_b, encout, hidden, eproj);
  // 6. dec_wih -> bf16 (aliased over dead xemb), then encxw + xpe GEMMs
  hipLaunchKernelGGL(cvt_k, dim3((NG*LDW/8+255)/256), dim3(256), 0, stream, dec_wih, dwih_b, NG*LDW/8);
  hipLaunchKernelGGL(gemm_bt, dim3(NG/128, (NB*NS+127)/128), dim3(256), 0, stream,
                     encout, NH2, dwih_b + NE, LDW, (const float*)nullptr, encxw, (float*)nullptr, NB*NS, NG, NH2, 0);
  hipLaunchKernelGGL(gemm_bt, dim3(NG/128, (NB*NTD+127)/128), dim3(256), 0, stream,
                     embin, NE, dwih_b, LDW, dec_bih, xpe, (float*)nullptr, NB*NTD, NG, NE, 0);
  hipLaunchKernelGGL(ufill_k, dim3((NB*NTD*16+255)/256), dim3(256), 0, stream, embin, U);
  // 7. decoder recurrence -> U[:, 0:768]
  hipLaunchKernelGGL(dec_k, dim3(NB), dim3(768), 0, stream,
                     hidden, eproj, encout, encxw, xpe, wt + (size_t)2*NG*NH, dec_bhh, attn_w, U);
  // 8. dec_fc_w -> bf16 (aliased over dead region), then big output projection (f32 out)
  hipLaunchKernelGGL(cvt_k, dim3((NV*KFC/8+255)/256), dim3(256), 0, stream, dec_fc_w, dfc_b, NV*KFC/8);
  hipLaunchKernelGGL(gemm_bt, dim3((NV+127)/128, (NB*NTD+127)/128), dim3(256), 0, stream,
                     U, KFC, dfc_b, KFC, dec_fc_b, (u16*)nullptr, out, NB*NTD, NV, KFC, 1);
}